// Round 4
// baseline (273.486 us; speedup 1.0000x reference)
//
#include <hip/hip_runtime.h>
#include <hip/hip_bf16.h>

// Problem constants
#define NROW 8192
#define DDIM 512
#define TEMP_INV 20.0f      // 1/0.05
#define SHIFT 20.0f         // sim <= 20, accumulate exp(sim-20)

// GEMM geometry: 256x256 tile, BK=64, 8 waves (2M x 4N), 2-buffer LDS,
// 8-phase interleave per 2 K-tiles (m201 template adapted to K=512).
#define BM 256
#define BN 256
#define BK 64
#define KT (DDIM / BK)            // 8 K-tiles
#define TILE_A_ELE (BM * BK)      // 16384 bf16 (A region; B same)
#define BUF_ELE (2 * TILE_A_ELE)  // A+B per buffer
#define LDS_BYTES (2 * BUF_ELE * 2)  // 131072

typedef __attribute__((ext_vector_type(8))) short short8;
typedef __attribute__((ext_vector_type(4))) float f32x4;

__device__ __forceinline__ void gload16(const __hip_bfloat16* g, __hip_bfloat16* l) {
  __builtin_amdgcn_global_load_lds(
      (const __attribute__((address_space(1))) void*)g,
      (__attribute__((address_space(3))) void*)l,
      16, 0, 0);
}

// -------------------------------------------------------------------------
// Kernel 1: row-normalize both inputs to bf16 (z1 additionally scaled by
// 1/temperature), zero the rowsum accumulator. One wave per row.
// -------------------------------------------------------------------------
__global__ __launch_bounds__(256) void normalize_rows(
    const float* __restrict__ z1, const float* __restrict__ z2,
    __hip_bfloat16* __restrict__ z1n, __hip_bfloat16* __restrict__ z2n,
    float* __restrict__ rowsum) {
  int row = blockIdx.x * 4 + (threadIdx.x >> 6);   // 0..16383
  int lane = threadIdx.x & 63;

  const float* src;
  __hip_bfloat16* dst;
  float numer;
  if (row < NROW) {
    src = z1 + (size_t)row * DDIM;
    dst = z1n + (size_t)row * DDIM;
    numer = TEMP_INV;
    if (lane == 0) rowsum[row] = 0.0f;
  } else {
    int r = row - NROW;
    src = z2 + (size_t)r * DDIM;
    dst = z2n + (size_t)r * DDIM;
    numer = 1.0f;
  }

  float4 v0 = *reinterpret_cast<const float4*>(src + lane * 8);
  float4 v1 = *reinterpret_cast<const float4*>(src + lane * 8 + 4);
  float ss = v0.x * v0.x + v0.y * v0.y + v0.z * v0.z + v0.w * v0.w +
             v1.x * v1.x + v1.y * v1.y + v1.z * v1.z + v1.w * v1.w;
#pragma unroll
  for (int off = 32; off; off >>= 1) ss += __shfl_xor(ss, off);

  float scale = numer / fmaxf(sqrtf(ss), 1e-8f);

  float vals[8] = {v0.x, v0.y, v0.z, v0.w, v1.x, v1.y, v1.z, v1.w};
  union { __hip_bfloat16 h[8]; uint4 q; } pk;
#pragma unroll
  for (int j = 0; j < 8; ++j) pk.h[j] = __float2bfloat16(vals[j] * scale);
  *reinterpret_cast<uint4*>(dst + lane * 8) = pk.q;
}

// -------------------------------------------------------------------------
// Kernel 2: fused GEMM (dots = z1n @ z2n^T) + exp epilogue + per-row
// sum-of-exp atomic accumulation. 8-phase pipelined 256x256 tile.
// Swizzle: LDS[row][slot'] holds global 16B-slot slot'^(row&7); staged via
// linear global_load_lds dest + pre-swizzled global source (verified 0
// bank conflicts in round 1).
// -------------------------------------------------------------------------
#define MFMA_Q(A_, B_, QM, QN)                                                 \
  do {                                                                         \
    __builtin_amdgcn_s_setprio(1);                                             \
    _Pragma("unroll") for (int mi = 0; mi < 4; ++mi) {                         \
      _Pragma("unroll") for (int ni = 0; ni < 2; ++ni) {                       \
        _Pragma("unroll") for (int kk = 0; kk < 2; ++kk) {                     \
          acc[(QM) * 4 + mi][(QN) * 2 + ni] =                                  \
              __builtin_amdgcn_mfma_f32_16x16x32_bf16(                         \
                  (A_)[mi * 2 + kk], (B_)[ni * 2 + kk],                        \
                  acc[(QM) * 4 + mi][(QN) * 2 + ni], 0, 0, 0);                 \
        }                                                                      \
      }                                                                        \
    }                                                                          \
    __builtin_amdgcn_s_setprio(0);                                             \
  } while (0)

#define BAR_PRE()                                                \
  do {                                                           \
    __builtin_amdgcn_s_barrier();                                \
    asm volatile("s_waitcnt lgkmcnt(0)" ::: "memory");           \
    __builtin_amdgcn_sched_barrier(0);                           \
  } while (0)

#define BAR_POST() __builtin_amdgcn_s_barrier()

#define VMC(N) asm volatile("s_waitcnt vmcnt(" #N ")" ::: "memory")

__global__ __launch_bounds__(512, 2) void gemm_lse(
    const __hip_bfloat16* __restrict__ An,   // z1n [N][D]
    const __hip_bfloat16* __restrict__ Bn,   // z2n [N][D]
    float* __restrict__ rowsum) {
  extern __shared__ __align__(16) __hip_bfloat16 lds[];

  const int bid = blockIdx.x;
  const int bx = bid & 31;
  const int by = bid >> 5;
  const int brow = by * BM;
  const int bcol = bx * BN;

  const int tid = threadIdx.x;
  const int w = tid >> 6;             // wave 0..7
  const int lane = tid & 63;
  const int wr = w >> 2;              // 0..1: rows [wr*128, +128)
  const int wc = w & 3;               // 0..3: cols [wc*64, +64)

  f32x4 acc[8][4];
#pragma unroll
  for (int m = 0; m < 8; ++m)
#pragma unroll
    for (int n = 0; n < 4; ++n) acc[m][n] = (f32x4)0.0f;

  // ---- staging (per-wave: 2 gloads per half; halves: 0=Atop 1=Abot 2=Btop 3=Bbot)
  const int srow8 = lane >> 3;               // 0..7
  const int sslot = (lane & 7) ^ srow8;      // pre-swizzled source slot

  auto STAGE_HALF = [&](int st, int h) {
    const int stm = st & (KT - 1);           // wrap: dead prefetch on last iter
    const __hip_bfloat16* gbase =
        (h < 2) ? An + (size_t)brow * DDIM : Bn + (size_t)bcol * DDIM;
    const int rowt = (h & 1) * 128 + w * 16; // row within 256-row tile
    const __hip_bfloat16* g =
        gbase + (size_t)(rowt + srow8) * DDIM + stm * BK + sslot * 8;
    __hip_bfloat16* dst = lds + (size_t)(stm & 1) * BUF_ELE +
                          ((h >= 2) ? TILE_A_ELE : 0) + rowt * BK;
    gload16(g, dst);
    gload16(g + (size_t)8 * DDIM, dst + 8 * BK);
  };

  // ---- fragment reads (b128, swizzled slot) ----
  const int hi = lane >> 4;    // 0..3
  const int l15 = lane & 15;
  const int x7 = lane & 7;

  auto READ_A = [&](short8* dst, int bufb, int qm) {
#pragma unroll
    for (int mi = 0; mi < 4; ++mi)
#pragma unroll
      for (int kk = 0; kk < 2; ++kk) {
        int row = wr * 128 + qm * 64 + mi * 16 + l15;
        int sl = ((kk * 4 + hi) ^ x7) * 8;
        dst[mi * 2 + kk] = *reinterpret_cast<const short8*>(
            &lds[(size_t)bufb * BUF_ELE + row * BK + sl]);
      }
  };
  auto READ_B = [&](short8* dst, int bufb, int qn) {
#pragma unroll
    for (int ni = 0; ni < 2; ++ni)
#pragma unroll
      for (int kk = 0; kk < 2; ++kk) {
        int row = wc * 64 + qn * 32 + ni * 16 + l15;
        int sl = ((kk * 4 + hi) ^ x7) * 8;
        dst[ni * 2 + kk] = *reinterpret_cast<const short8*>(
            &lds[(size_t)bufb * BUF_ELE + TILE_A_ELE + row * BK + sl]);
      }
  };

  // ---- prologue: tile0 fully + tile1 h0,h1; keep 2 halves in flight ----
  STAGE_HALF(0, 0); STAGE_HALF(0, 1); STAGE_HALF(0, 2); STAGE_HALF(0, 3);
  STAGE_HALF(1, 0); STAGE_HALF(1, 1);
  VMC(4);
  __builtin_amdgcn_s_barrier();
  __builtin_amdgcn_sched_barrier(0);

  short8 af0[8], af1[8], bf0[4], bf1[4];

#pragma unroll
  for (int i = 0; i < KT / 2; ++i) {
    // Tiles: T0 = 2i (buf0), T1 = 2i+1 (buf1).
    // ph1: read buf0 qm0/qn0 frags; stage T1.h2
    READ_A(af0, 0, 0); READ_B(bf0, 0, 0);
    STAGE_HALF(2 * i + 1, 2);
    BAR_PRE();  MFMA_Q(af0, bf0, 0, 0);  BAR_POST();
    // ph2: read buf0 qm1/qn1; stage T1.h3  (buf0 fully read after this)
    READ_A(af1, 0, 1); READ_B(bf1, 0, 1);
    STAGE_HALF(2 * i + 1, 3);
    BAR_PRE();  MFMA_Q(af1, bf1, 1, 1);  BAR_POST();
    // ph3: stage T2.h0 into buf0 (free now)
    STAGE_HALF(2 * i + 2, 0);
    BAR_PRE();  MFMA_Q(af1, bf0, 1, 0);  BAR_POST();
    // ph4: stage T2.h1; counted wait -> T1's 4 halves landed
    STAGE_HALF(2 * i + 2, 1);
    VMC(4);
    BAR_PRE();  MFMA_Q(af0, bf1, 0, 1);  BAR_POST();
    // ph5: read buf1 qm0/qn0; stage T2.h2
    READ_A(af0, 1, 0); READ_B(bf0, 1, 0);
    STAGE_HALF(2 * i + 2, 2);
    BAR_PRE();  MFMA_Q(af0, bf0, 0, 0);  BAR_POST();
    // ph6: read buf1 qm1/qn1; stage T2.h3  (buf1 fully read after this)
    READ_A(af1, 1, 1); READ_B(bf1, 1, 1);
    STAGE_HALF(2 * i + 2, 3);
    BAR_PRE();  MFMA_Q(af1, bf1, 1, 1);  BAR_POST();
    // ph7: stage T3.h0 into buf1 (free now)
    STAGE_HALF(2 * i + 3, 0);
    BAR_PRE();  MFMA_Q(af1, bf0, 1, 0);  BAR_POST();
    // ph8: stage T3.h1; counted wait -> T2's 4 halves landed
    STAGE_HALF(2 * i + 3, 1);
    VMC(4);
    BAR_PRE();  MFMA_Q(af0, bf1, 0, 1);  BAR_POST();
  }

  // ---- epilogue: exp(sim - 20), 16-lane col reduce, atomic accumulate ----
  // C/D layout: col = lane&15, row = (lane>>4)*4 + reg  [m89/m91]
  const float L2E = 1.4426950408889634f;
  const float NEG = -SHIFT * 1.4426950408889634f;
#pragma unroll
  for (int m = 0; m < 8; ++m) {
#pragma unroll
    for (int r = 0; r < 4; ++r) {
      float s = 0.0f;
#pragma unroll
      for (int n = 0; n < 4; ++n)
        s += exp2f(fmaf(acc[m][n][r], L2E, NEG));
      s += __shfl_xor(s, 1);
      s += __shfl_xor(s, 2);
      s += __shfl_xor(s, 4);
      s += __shfl_xor(s, 8);
      if (l15 == 0)
        atomicAdd(&rowsum[brow + wr * 128 + m * 16 + hi * 4 + r], s);
    }
  }
}

// -------------------------------------------------------------------------
// Kernel 3: out = -( mean_i( log(rowsum_i) + 20 ) )
// -------------------------------------------------------------------------
__global__ __launch_bounds__(1024) void finalize_lse(
    const float* __restrict__ rowsum, float* __restrict__ out) {
  __shared__ float sm[16];
  float s = 0.0f;
  for (int i = threadIdx.x; i < NROW; i += 1024) s += logf(rowsum[i]);
#pragma unroll
  for (int off = 32; off; off >>= 1) s += __shfl_xor(s, off);
  int w = threadIdx.x >> 6;
  if ((threadIdx.x & 63) == 0) sm[w] = s;
  __syncthreads();
  if (threadIdx.x == 0) {
    float t = 0.0f;
#pragma unroll
    for (int i = 0; i < 16; ++i) t += sm[i];
    out[0] = -(t / (float)NROW + SHIFT);
  }
}

// -------------------------------------------------------------------------
extern "C" void kernel_launch(void* const* d_in, const int* in_sizes, int n_in,
                              void* d_out, int out_size, void* d_ws,
                              size_t ws_size, hipStream_t stream) {
  const float* z1 = (const float*)d_in[0];
  const float* z2 = (const float*)d_in[1];
  float* out = (float*)d_out;

  char* ws = (char*)d_ws;
  __hip_bfloat16* z1n = (__hip_bfloat16*)ws;                               // 8 MB
  __hip_bfloat16* z2n = (__hip_bfloat16*)(ws + (size_t)NROW * DDIM * 2);   // 8 MB
  float* rowsum = (float*)(ws + (size_t)2 * NROW * DDIM * 2);              // 32 KB

  static bool attr_set = false;
  if (!attr_set) {
    hipFuncSetAttribute((const void*)gemm_lse,
                        hipFuncAttributeMaxDynamicSharedMemorySize, LDS_BYTES);
    attr_set = true;
  }

  normalize_rows<<<dim3((2 * NROW) / 4), dim3(256), 0, stream>>>(z1, z2, z1n,
                                                                 z2n, rowsum);
  gemm_lse<<<dim3((NROW / BM) * (NROW / BN)), dim3(512), LDS_BYTES, stream>>>(
      z1n, z2n, rowsum);
  finalize_lse<<<dim3(1), dim3(1024), 0, stream>>>(rowsum, out);
}

// Round 5
// 204.365 us; speedup vs baseline: 1.3382x; 1.3382x over previous
//
#include <hip/hip_runtime.h>
#include <hip/hip_bf16.h>

// Problem constants
#define NROW 8192
#define DDIM 512
#define TEMP_INV 20.0f      // 1/0.05
#define SHIFT 20.0f         // sim <= 20, accumulate exp(sim-20)

// GEMM geometry: 256x256 tile, BK=64, 8 waves (2M x 4N), 2-buffer LDS,
// 8-phase interleave per 2 K-tiles. Fragments read per-phase with short
// live ranges (peak 64 VGPR of frags) -- round-4's cross-phase frag
// caching spilled to scratch (WRITE_SIZE 133MB) and halved MfmaUtil.
#define BM 256
#define BN 256
#define BK 64
#define KT (DDIM / BK)            // 8 K-tiles
#define TILE_A_ELE (BM * BK)      // 16384 bf16 (A region; B same)
#define BUF_ELE (2 * TILE_A_ELE)  // A+B per buffer
#define LDS_BYTES (2 * BUF_ELE * 2)  // 131072

typedef __attribute__((ext_vector_type(8))) short short8;
typedef __attribute__((ext_vector_type(4))) float f32x4;

__device__ __forceinline__ void gload16(const __hip_bfloat16* g, __hip_bfloat16* l) {
  __builtin_amdgcn_global_load_lds(
      (const __attribute__((address_space(1))) void*)g,
      (__attribute__((address_space(3))) void*)l,
      16, 0, 0);
}

// -------------------------------------------------------------------------
// Kernel 1: row-normalize both inputs to bf16 (z1 additionally scaled by
// 1/temperature), zero the rowsum accumulator. One wave per row.
// -------------------------------------------------------------------------
__global__ __launch_bounds__(256) void normalize_rows(
    const float* __restrict__ z1, const float* __restrict__ z2,
    __hip_bfloat16* __restrict__ z1n, __hip_bfloat16* __restrict__ z2n,
    float* __restrict__ rowsum) {
  int row = blockIdx.x * 4 + (threadIdx.x >> 6);   // 0..16383
  int lane = threadIdx.x & 63;

  const float* src;
  __hip_bfloat16* dst;
  float numer;
  if (row < NROW) {
    src = z1 + (size_t)row * DDIM;
    dst = z1n + (size_t)row * DDIM;
    numer = TEMP_INV;
    if (lane == 0) rowsum[row] = 0.0f;
  } else {
    int r = row - NROW;
    src = z2 + (size_t)r * DDIM;
    dst = z2n + (size_t)r * DDIM;
    numer = 1.0f;
  }

  float4 v0 = *reinterpret_cast<const float4*>(src + lane * 8);
  float4 v1 = *reinterpret_cast<const float4*>(src + lane * 8 + 4);
  float ss = v0.x * v0.x + v0.y * v0.y + v0.z * v0.z + v0.w * v0.w +
             v1.x * v1.x + v1.y * v1.y + v1.z * v1.z + v1.w * v1.w;
#pragma unroll
  for (int off = 32; off; off >>= 1) ss += __shfl_xor(ss, off);

  float scale = numer / fmaxf(sqrtf(ss), 1e-8f);

  float vals[8] = {v0.x, v0.y, v0.z, v0.w, v1.x, v1.y, v1.z, v1.w};
  union { __hip_bfloat16 h[8]; uint4 q; } pk;
#pragma unroll
  for (int j = 0; j < 8; ++j) pk.h[j] = __float2bfloat16(vals[j] * scale);
  *reinterpret_cast<uint4*>(dst + lane * 8) = pk.q;
}

// -------------------------------------------------------------------------
// Kernel 2: fused GEMM (dots = z1n @ z2n^T) + exp epilogue + per-row
// sum-of-exp atomic accumulation. 8-phase pipelined 256x256 tile.
// Swizzle: LDS[row][slot'] holds global 16B-slot slot'^(row&7); staged via
// linear global_load_lds dest + pre-swizzled global source (0 conflicts,
// verified rounds 1 & 4).
// -------------------------------------------------------------------------
#define MFMA_Q(A_, B_, QM, QN)                                                 \
  do {                                                                         \
    __builtin_amdgcn_s_setprio(1);                                             \
    _Pragma("unroll") for (int mi = 0; mi < 4; ++mi) {                         \
      _Pragma("unroll") for (int ni = 0; ni < 2; ++ni) {                       \
        _Pragma("unroll") for (int kk = 0; kk < 2; ++kk) {                     \
          acc[(QM) * 4 + mi][(QN) * 2 + ni] =                                  \
              __builtin_amdgcn_mfma_f32_16x16x32_bf16(                         \
                  (A_)[mi * 2 + kk], (B_)[ni * 2 + kk],                        \
                  acc[(QM) * 4 + mi][(QN) * 2 + ni], 0, 0, 0);                 \
        }                                                                      \
      }                                                                        \
    }                                                                          \
    __builtin_amdgcn_s_setprio(0);                                             \
  } while (0)

#define BAR_PRE()                                                \
  do {                                                           \
    __builtin_amdgcn_s_barrier();                                \
    asm volatile("s_waitcnt lgkmcnt(0)" ::: "memory");           \
    __builtin_amdgcn_sched_barrier(0);                           \
  } while (0)

#define BAR_POST() __builtin_amdgcn_s_barrier()

#define VMC(N) asm volatile("s_waitcnt vmcnt(" #N ")" ::: "memory")

__global__ __launch_bounds__(512, 2) void gemm_lse(
    const __hip_bfloat16* __restrict__ An,   // z1n [N][D]
    const __hip_bfloat16* __restrict__ Bn,   // z2n [N][D]
    float* __restrict__ rowsum) {
  extern __shared__ __align__(16) __hip_bfloat16 lds[];

  const int bid = blockIdx.x;
  const int bx = bid & 31;
  const int by = bid >> 5;
  const int brow = by * BM;
  const int bcol = bx * BN;

  const int tid = threadIdx.x;
  const int w = tid >> 6;             // wave 0..7
  const int lane = tid & 63;
  const int wr = w >> 2;              // 0..1: rows [wr*128, +128)
  const int wc = w & 3;               // 0..3: cols [wc*64, +64)

  f32x4 acc[8][4];
#pragma unroll
  for (int m = 0; m < 8; ++m)
#pragma unroll
    for (int n = 0; n < 4; ++n) acc[m][n] = (f32x4)0.0f;

  // ---- staging (per-wave: 2 gloads per half; halves: 0=Atop 1=Abot 2=Btop 3=Bbot)
  const int srow8 = lane >> 3;               // 0..7
  const int sslot = (lane & 7) ^ srow8;      // pre-swizzled source slot

  auto STAGE_HALF = [&](int st, int h) {
    const int stm = st & (KT - 1);           // wrap: dead prefetch on last iter
    const __hip_bfloat16* gbase =
        (h < 2) ? An + (size_t)brow * DDIM : Bn + (size_t)bcol * DDIM;
    const int rowt = (h & 1) * 128 + w * 16; // row within 256-row tile
    const __hip_bfloat16* g =
        gbase + (size_t)(rowt + srow8) * DDIM + stm * BK + sslot * 8;
    __hip_bfloat16* dst = lds + (size_t)(stm & 1) * BUF_ELE +
                          ((h >= 2) ? TILE_A_ELE : 0) + rowt * BK;
    gload16(g, dst);
    gload16(g + (size_t)8 * DDIM, dst + 8 * BK);
  };

  // ---- fragment reads (b128, swizzled slot), consumed same/next phase ----
  const int hi = lane >> 4;    // 0..3
  const int l15 = lane & 15;
  const int x7 = lane & 7;

  auto READ_A = [&](short8* dst, int bufb, int qm) {
#pragma unroll
    for (int mi = 0; mi < 4; ++mi)
#pragma unroll
      for (int kk = 0; kk < 2; ++kk) {
        int row = wr * 128 + qm * 64 + mi * 16 + l15;
        int sl = ((kk * 4 + hi) ^ x7) * 8;
        dst[mi * 2 + kk] = *reinterpret_cast<const short8*>(
            &lds[(size_t)bufb * BUF_ELE + row * BK + sl]);
      }
  };
  auto READ_B = [&](short8* dst, int bufb, int qn) {
#pragma unroll
    for (int ni = 0; ni < 2; ++ni)
#pragma unroll
      for (int kk = 0; kk < 2; ++kk) {
        int row = wc * 64 + qn * 32 + ni * 16 + l15;
        int sl = ((kk * 4 + hi) ^ x7) * 8;
        dst[ni * 2 + kk] = *reinterpret_cast<const short8*>(
            &lds[(size_t)bufb * BUF_ELE + TILE_A_ELE + row * BK + sl]);
      }
  };

  // ---- prologue: tile0 fully + tile1 h0; 1 half in flight after wait ----
  STAGE_HALF(0, 0); STAGE_HALF(0, 1); STAGE_HALF(0, 2); STAGE_HALF(0, 3);
  STAGE_HALF(1, 0);
  VMC(2);                              // tile0's 4 halves landed
  __builtin_amdgcn_s_barrier();
  __builtin_amdgcn_sched_barrier(0);

  // af reused for A-quadrant 0 then 1 (structurally caps live frags at 64
  // VGPR: af 32 + bf0 16 + bf1 16). acc -> AGPRs.
  short8 af[8], bf0[4], bf1[4];

#pragma unroll
  for (int i = 0; i < KT / 2; ++i) {
    // Tiles: T0 = 2i (buf0, ph1-4), T1 = 2i+1 (buf1, ph5-8).
    // Staging: 1 half/phase. T1.h1-h3 @ ph1-3; T2.h0-h3 @ ph4-7; T3.h0 @ ph8.
    // Buffer-free proof: buf0's last ds_read is ph3 (stage into buf0 from
    // ph4 on); buf1's last ds_read is ph7 (stage into buf1 at ph8/ph1-3).
    // ph1: q(0,0) of T0; reads A0+B0 (12 x b128)
    READ_A(af, 0, 0); READ_B(bf0, 0, 0);
    STAGE_HALF(2 * i + 1, 1);
    BAR_PRE();  MFMA_Q(af, bf0, 0, 0);  BAR_POST();
    // ph2: q(0,1); reads B1 (4)
    READ_B(bf1, 0, 1);
    STAGE_HALF(2 * i + 1, 2);
    BAR_PRE();  MFMA_Q(af, bf1, 0, 1);  BAR_POST();
    // ph3: q(1,0); reads A1 (8, overwrites af)
    READ_A(af, 0, 1);
    STAGE_HALF(2 * i + 1, 3);
    BAR_PRE();  MFMA_Q(af, bf0, 1, 0);  BAR_POST();
    // ph4: q(1,1); no reads; counted wait -> T1's halves landed
    STAGE_HALF(2 * i + 2, 0);
    VMC(2);
    BAR_PRE();  MFMA_Q(af, bf1, 1, 1);  BAR_POST();
    // ph5: q(0,0) of T1 (buf1)
    READ_A(af, 1, 0); READ_B(bf0, 1, 0);
    STAGE_HALF(2 * i + 2, 1);
    BAR_PRE();  MFMA_Q(af, bf0, 0, 0);  BAR_POST();
    // ph6: q(0,1)
    READ_B(bf1, 1, 1);
    STAGE_HALF(2 * i + 2, 2);
    BAR_PRE();  MFMA_Q(af, bf1, 0, 1);  BAR_POST();
    // ph7: q(1,0)
    READ_A(af, 1, 1);
    STAGE_HALF(2 * i + 2, 3);
    BAR_PRE();  MFMA_Q(af, bf0, 1, 0);  BAR_POST();
    // ph8: q(1,1); counted wait -> T2's halves landed
    STAGE_HALF(2 * i + 3, 0);
    VMC(2);
    BAR_PRE();  MFMA_Q(af, bf1, 1, 1);  BAR_POST();
  }

  // ---- epilogue: exp(sim - 20), 16-lane col reduce, atomic accumulate ----
  // C/D layout: col = lane&15, row = (lane>>4)*4 + reg  [m89/m91]
  const float L2E = 1.4426950408889634f;
  const float NEG = -SHIFT * 1.4426950408889634f;
#pragma unroll
  for (int m = 0; m < 8; ++m) {
#pragma unroll
    for (int r = 0; r < 4; ++r) {
      float s = 0.0f;
#pragma unroll
      for (int n = 0; n < 4; ++n)
        s += exp2f(fmaf(acc[m][n][r], L2E, NEG));
      s += __shfl_xor(s, 1);
      s += __shfl_xor(s, 2);
      s += __shfl_xor(s, 4);
      s += __shfl_xor(s, 8);
      if (l15 == 0)
        atomicAdd(&rowsum[brow + wr * 128 + m * 16 + hi * 4 + r], s);
    }
  }
}

// -------------------------------------------------------------------------
// Kernel 3: out = -( mean_i( log(rowsum_i) + 20 ) )
// -------------------------------------------------------------------------
__global__ __launch_bounds__(1024) void finalize_lse(
    const float* __restrict__ rowsum, float* __restrict__ out) {
  __shared__ float sm[16];
  float s = 0.0f;
  for (int i = threadIdx.x; i < NROW; i += 1024) s += logf(rowsum[i]);
#pragma unroll
  for (int off = 32; off; off >>= 1) s += __shfl_xor(s, off);
  int w = threadIdx.x >> 6;
  if ((threadIdx.x & 63) == 0) sm[w] = s;
  __syncthreads();
  if (threadIdx.x == 0) {
    float t = 0.0f;
#pragma unroll
    for (int i = 0; i < 16; ++i) t += sm[i];
    out[0] = -(t / (float)NROW + SHIFT);
  }
}

// -------------------------------------------------------------------------
extern "C" void kernel_launch(void* const* d_in, const int* in_sizes, int n_in,
                              void* d_out, int out_size, void* d_ws,
                              size_t ws_size, hipStream_t stream) {
  const float* z1 = (const float*)d_in[0];
  const float* z2 = (const float*)d_in[1];
  float* out = (float*)d_out;

  char* ws = (char*)d_ws;
  __hip_bfloat16* z1n = (__hip_bfloat16*)ws;                               // 8 MB
  __hip_bfloat16* z2n = (__hip_bfloat16*)(ws + (size_t)NROW * DDIM * 2);   // 8 MB
  float* rowsum = (float*)(ws + (size_t)2 * NROW * DDIM * 2);              // 32 KB

  static bool attr_set = false;
  if (!attr_set) {
    hipFuncSetAttribute((const void*)gemm_lse,
                        hipFuncAttributeMaxDynamicSharedMemorySize, LDS_BYTES);
    attr_set = true;
  }

  normalize_rows<<<dim3((2 * NROW) / 4), dim3(256), 0, stream>>>(z1, z2, z1n,
                                                                 z2n, rowsum);
  gemm_lse<<<dim3((NROW / BM) * (NROW / BN)), dim3(512), LDS_BYTES, stream>>>(
      z1n, z2n, rowsum);
  finalize_lse<<<dim3(1), dim3(1024), 0, stream>>>(rowsum, out);
}

// Round 6
// 162.263 us; speedup vs baseline: 1.6854x; 1.2595x over previous
//
#include <hip/hip_runtime.h>
#include <hip/hip_bf16.h>

// Problem constants
#define NROW 8192
#define DDIM 512
#define TEMP_INV 20.0f      // 1/0.05
#define SHIFT 20.0f         // sim <= 20, accumulate exp(sim-20)

// GEMM geometry: 256x256 tile, BK=64, 8 waves (2M x 4N), 2-buffer LDS,
// 8-phase interleave per 2 K-tiles. Round-5 analysis: operand staging was
// LLC-bound (512MB @ 3.6TB/s = 143us) because per-XCD working set (~10MB)
// blew past the 4MB XCD L2. Round 6 adds an XCD-aware 4x4-supertile
// swizzle (2MB panel set per supertile) to make staging L2-resident.
#define BM 256
#define BN 256
#define BK 64
#define KT (DDIM / BK)            // 8 K-tiles
#define TILE_A_ELE (BM * BK)      // 16384 bf16 (A region; B same)
#define BUF_ELE (2 * TILE_A_ELE)  // A+B per buffer
#define LDS_BYTES (2 * BUF_ELE * 2)  // 131072

typedef __attribute__((ext_vector_type(8))) short short8;
typedef __attribute__((ext_vector_type(4))) float f32x4;

__device__ __forceinline__ void gload16(const __hip_bfloat16* g, __hip_bfloat16* l) {
  __builtin_amdgcn_global_load_lds(
      (const __attribute__((address_space(1))) void*)g,
      (__attribute__((address_space(3))) void*)l,
      16, 0, 0);
}

// -------------------------------------------------------------------------
// Kernel 1: row-normalize both inputs to bf16 (z1 additionally scaled by
// 1/temperature), zero the rowsum accumulator. One wave per row.
// -------------------------------------------------------------------------
__global__ __launch_bounds__(256) void normalize_rows(
    const float* __restrict__ z1, const float* __restrict__ z2,
    __hip_bfloat16* __restrict__ z1n, __hip_bfloat16* __restrict__ z2n,
    float* __restrict__ rowsum) {
  int row = blockIdx.x * 4 + (threadIdx.x >> 6);   // 0..16383
  int lane = threadIdx.x & 63;

  const float* src;
  __hip_bfloat16* dst;
  float numer;
  if (row < NROW) {
    src = z1 + (size_t)row * DDIM;
    dst = z1n + (size_t)row * DDIM;
    numer = TEMP_INV;
    if (lane == 0) rowsum[row] = 0.0f;
  } else {
    int r = row - NROW;
    src = z2 + (size_t)r * DDIM;
    dst = z2n + (size_t)r * DDIM;
    numer = 1.0f;
  }

  float4 v0 = *reinterpret_cast<const float4*>(src + lane * 8);
  float4 v1 = *reinterpret_cast<const float4*>(src + lane * 8 + 4);
  float ss = v0.x * v0.x + v0.y * v0.y + v0.z * v0.z + v0.w * v0.w +
             v1.x * v1.x + v1.y * v1.y + v1.z * v1.z + v1.w * v1.w;
#pragma unroll
  for (int off = 32; off; off >>= 1) ss += __shfl_xor(ss, off);

  float scale = numer / fmaxf(sqrtf(ss), 1e-8f);

  float vals[8] = {v0.x, v0.y, v0.z, v0.w, v1.x, v1.y, v1.z, v1.w};
  union { __hip_bfloat16 h[8]; uint4 q; } pk;
#pragma unroll
  for (int j = 0; j < 8; ++j) pk.h[j] = __float2bfloat16(vals[j] * scale);
  *reinterpret_cast<uint4*>(dst + lane * 8) = pk.q;
}

// -------------------------------------------------------------------------
// Kernel 2: fused GEMM (dots = z1n @ z2n^T) + exp epilogue + per-row
// sum-of-exp atomic accumulation. 8-phase pipelined 256x256 tile.
// Swizzle: LDS[row][slot'] holds global 16B-slot slot'^(row&7); staged via
// linear global_load_lds dest + pre-swizzled global source (0 conflicts,
// verified rounds 1/4/5).
// -------------------------------------------------------------------------
#define MFMA_Q(A_, B_, QM, QN)                                                 \
  do {                                                                         \
    __builtin_amdgcn_s_setprio(1);                                             \
    _Pragma("unroll") for (int mi = 0; mi < 4; ++mi) {                         \
      _Pragma("unroll") for (int ni = 0; ni < 2; ++ni) {                       \
        _Pragma("unroll") for (int kk = 0; kk < 2; ++kk) {                     \
          acc[(QM) * 4 + mi][(QN) * 2 + ni] =                                  \
              __builtin_amdgcn_mfma_f32_16x16x32_bf16(                         \
                  (A_)[mi * 2 + kk], (B_)[ni * 2 + kk],                        \
                  acc[(QM) * 4 + mi][(QN) * 2 + ni], 0, 0, 0);                 \
        }                                                                      \
      }                                                                        \
    }                                                                          \
    __builtin_amdgcn_s_setprio(0);                                             \
  } while (0)

#define BAR_PRE()                                                \
  do {                                                           \
    __builtin_amdgcn_s_barrier();                                \
    asm volatile("s_waitcnt lgkmcnt(0)" ::: "memory");           \
    __builtin_amdgcn_sched_barrier(0);                           \
  } while (0)

#define BAR_POST() __builtin_amdgcn_s_barrier()

#define VMC(N) asm volatile("s_waitcnt vmcnt(" #N ")" ::: "memory")

__global__ __launch_bounds__(512, 2) void gemm_lse(
    const __hip_bfloat16* __restrict__ An,   // z1n [N][D]
    const __hip_bfloat16* __restrict__ Bn,   // z2n [N][D]
    float* __restrict__ rowsum) {
  extern __shared__ __align__(16) __hip_bfloat16 lds[];

  // ---- XCD-aware supertile swizzle (bijective over the 32x32 grid) ----
  // Observed dispatch: xcd = bid & 7. Give each XCD 4 contiguous grid-rows
  // (chunk) walked in 4x4 supertiles: 4 A-panels + 4 B-panels = 2 MB fits
  // the 4 MB XCD L2; A-panels persist across the whole chunk.
  const int bid = blockIdx.x;
  const int chunk = bid & 7;          // XCD id (round-robin dispatch)
  const int slot = bid >> 3;          // 0..127: per-XCD issue order
  const int by = chunk * 4 + ((slot >> 2) & 3);
  const int bx = (slot >> 4) * 4 + (slot & 3);
  const int brow = by * BM;
  const int bcol = bx * BN;

  const int tid = threadIdx.x;
  const int w = tid >> 6;             // wave 0..7
  const int lane = tid & 63;
  const int wr = w >> 2;              // 0..1: rows [wr*128, +128)
  const int wc = w & 3;               // 0..3: cols [wc*64, +64)

  f32x4 acc[8][4];
#pragma unroll
  for (int m = 0; m < 8; ++m)
#pragma unroll
    for (int n = 0; n < 4; ++n) acc[m][n] = (f32x4)0.0f;

  // ---- staging (per-wave: 2 gloads per half; halves: 0=Atop 1=Abot 2=Btop 3=Bbot)
  const int srow8 = lane >> 3;               // 0..7
  const int sslot = (lane & 7) ^ srow8;      // pre-swizzled source slot

  auto STAGE_HALF = [&](int st, int h) {
    const int stm = st & (KT - 1);           // wrap: dead prefetch on last iter
    const __hip_bfloat16* gbase =
        (h < 2) ? An + (size_t)brow * DDIM : Bn + (size_t)bcol * DDIM;
    const int rowt = (h & 1) * 128 + w * 16; // row within 256-row tile
    const __hip_bfloat16* g =
        gbase + (size_t)(rowt + srow8) * DDIM + stm * BK + sslot * 8;
    __hip_bfloat16* dst = lds + (size_t)(stm & 1) * BUF_ELE +
                          ((h >= 2) ? TILE_A_ELE : 0) + rowt * BK;
    gload16(g, dst);
    gload16(g + (size_t)8 * DDIM, dst + 8 * BK);
  };

  // ---- fragment reads (b128, swizzled slot), consumed same/next phase ----
  const int hi = lane >> 4;    // 0..3
  const int l15 = lane & 15;
  const int x7 = lane & 7;

  auto READ_A = [&](short8* dst, int bufb, int qm) {
#pragma unroll
    for (int mi = 0; mi < 4; ++mi)
#pragma unroll
      for (int kk = 0; kk < 2; ++kk) {
        int row = wr * 128 + qm * 64 + mi * 16 + l15;
        int sl = ((kk * 4 + hi) ^ x7) * 8;
        dst[mi * 2 + kk] = *reinterpret_cast<const short8*>(
            &lds[(size_t)bufb * BUF_ELE + row * BK + sl]);
      }
  };
  auto READ_B = [&](short8* dst, int bufb, int qn) {
#pragma unroll
    for (int ni = 0; ni < 2; ++ni)
#pragma unroll
      for (int kk = 0; kk < 2; ++kk) {
        int row = wc * 64 + qn * 32 + ni * 16 + l15;
        int sl = ((kk * 4 + hi) ^ x7) * 8;
        dst[ni * 2 + kk] = *reinterpret_cast<const short8*>(
            &lds[(size_t)bufb * BUF_ELE + TILE_A_ELE + row * BK + sl]);
      }
  };

  // ---- prologue: tile0 fully + tile1 h0; 1 half in flight after wait ----
  STAGE_HALF(0, 0); STAGE_HALF(0, 1); STAGE_HALF(0, 2); STAGE_HALF(0, 3);
  STAGE_HALF(1, 0);
  VMC(2);                              // tile0's 4 halves landed
  __builtin_amdgcn_s_barrier();
  __builtin_amdgcn_sched_barrier(0);

  // af reused for A-quadrant 0 then 1 (structurally caps live frags at 64
  // VGPR: af 32 + bf0 16 + bf1 16). acc -> AGPRs.
  short8 af[8], bf0[4], bf1[4];

#pragma unroll
  for (int i = 0; i < KT / 2; ++i) {
    // Tiles: T0 = 2i (buf0, ph1-4), T1 = 2i+1 (buf1, ph5-8).
    // Staging: 1 half/phase. T1.h1-h3 @ ph1-3; T2.h0-h3 @ ph4-7; T3.h0 @ ph8.
    // Buffer-free proof: buf0's last ds_read is ph3 (stage into buf0 from
    // ph4 on); buf1's last ds_read is ph7 (stage into buf1 at ph8/ph1-3).
    // ph1: q(0,0) of T0; reads A0+B0 (12 x b128)
    READ_A(af, 0, 0); READ_B(bf0, 0, 0);
    STAGE_HALF(2 * i + 1, 1);
    BAR_PRE();  MFMA_Q(af, bf0, 0, 0);  BAR_POST();
    // ph2: q(0,1); reads B1 (4)
    READ_B(bf1, 0, 1);
    STAGE_HALF(2 * i + 1, 2);
    BAR_PRE();  MFMA_Q(af, bf1, 0, 1);  BAR_POST();
    // ph3: q(1,0); reads A1 (8, overwrites af)
    READ_A(af, 0, 1);
    STAGE_HALF(2 * i + 1, 3);
    BAR_PRE();  MFMA_Q(af, bf0, 1, 0);  BAR_POST();
    // ph4: q(1,1); no reads; counted wait -> T1's halves landed
    STAGE_HALF(2 * i + 2, 0);
    VMC(2);
    BAR_PRE();  MFMA_Q(af, bf1, 1, 1);  BAR_POST();
    // ph5: q(0,0) of T1 (buf1)
    READ_A(af, 1, 0); READ_B(bf0, 1, 0);
    STAGE_HALF(2 * i + 2, 1);
    BAR_PRE();  MFMA_Q(af, bf0, 0, 0);  BAR_POST();
    // ph6: q(0,1)
    READ_B(bf1, 1, 1);
    STAGE_HALF(2 * i + 2, 2);
    BAR_PRE();  MFMA_Q(af, bf1, 0, 1);  BAR_POST();
    // ph7: q(1,0)
    READ_A(af, 1, 1);
    STAGE_HALF(2 * i + 2, 3);
    BAR_PRE();  MFMA_Q(af, bf0, 1, 0);  BAR_POST();
    // ph8: q(1,1); counted wait -> T2's halves landed
    STAGE_HALF(2 * i + 3, 0);
    VMC(2);
    BAR_PRE();  MFMA_Q(af, bf1, 1, 1);  BAR_POST();
  }

  // ---- epilogue: exp(sim - 20), 16-lane col reduce, atomic accumulate ----
  // C/D layout: col = lane&15, row = (lane>>4)*4 + reg  [m89/m91]
  const float L2E = 1.4426950408889634f;
  const float NEG = -SHIFT * 1.4426950408889634f;
#pragma unroll
  for (int m = 0; m < 8; ++m) {
#pragma unroll
    for (int r = 0; r < 4; ++r) {
      float s = 0.0f;
#pragma unroll
      for (int n = 0; n < 4; ++n)
        s += exp2f(fmaf(acc[m][n][r], L2E, NEG));
      s += __shfl_xor(s, 1);
      s += __shfl_xor(s, 2);
      s += __shfl_xor(s, 4);
      s += __shfl_xor(s, 8);
      if (l15 == 0)
        atomicAdd(&rowsum[brow + wr * 128 + m * 16 + hi * 4 + r], s);
    }
  }
}

// -------------------------------------------------------------------------
// Kernel 3: out = -( mean_i( log(rowsum_i) + 20 ) )
// -------------------------------------------------------------------------
__global__ __launch_bounds__(1024) void finalize_lse(
    const float* __restrict__ rowsum, float* __restrict__ out) {
  __shared__ float sm[16];
  float s = 0.0f;
  for (int i = threadIdx.x; i < NROW; i += 1024) s += logf(rowsum[i]);
#pragma unroll
  for (int off = 32; off; off >>= 1) s += __shfl_xor(s, off);
  int w = threadIdx.x >> 6;
  if ((threadIdx.x & 63) == 0) sm[w] = s;
  __syncthreads();
  if (threadIdx.x == 0) {
    float t = 0.0f;
#pragma unroll
    for (int i = 0; i < 16; ++i) t += sm[i];
    out[0] = -(t / (float)NROW + SHIFT);
  }
}

// -------------------------------------------------------------------------
extern "C" void kernel_launch(void* const* d_in, const int* in_sizes, int n_in,
                              void* d_out, int out_size, void* d_ws,
                              size_t ws_size, hipStream_t stream) {
  const float* z1 = (const float*)d_in[0];
  const float* z2 = (const float*)d_in[1];
  float* out = (float*)d_out;

  char* ws = (char*)d_ws;
  __hip_bfloat16* z1n = (__hip_bfloat16*)ws;                               // 8 MB
  __hip_bfloat16* z2n = (__hip_bfloat16*)(ws + (size_t)NROW * DDIM * 2);   // 8 MB
  float* rowsum = (float*)(ws + (size_t)2 * NROW * DDIM * 2);              // 32 KB

  static bool attr_set = false;
  if (!attr_set) {
    hipFuncSetAttribute((const void*)gemm_lse,
                        hipFuncAttributeMaxDynamicSharedMemorySize, LDS_BYTES);
    attr_set = true;
  }

  normalize_rows<<<dim3((2 * NROW) / 4), dim3(256), 0, stream>>>(z1, z2, z1n,
                                                                 z2n, rowsum);
  gemm_lse<<<dim3((NROW / BM) * (NROW / BN)), dim3(512), LDS_BYTES, stream>>>(
      z1n, z2n, rowsum);
  finalize_lse<<<dim3(1), dim3(1024), 0, stream>>>(rowsum, out);
}

// Round 8
// 160.210 us; speedup vs baseline: 1.7070x; 1.0128x over previous
//
#include <hip/hip_runtime.h>
#include <hip/hip_bf16.h>

// Problem constants
#define NROW 8192
#define DDIM 512
#define TEMP_INV 20.0f      // 1/0.05
#define SHIFT 20.0f         // sim <= 20, accumulate exp(sim-20)

// GEMM geometry: 256x256 tile, BK=64, 8 waves (2M x 4N), 2-buffer LDS,
// 8-phase interleave per 2 K-tiles, XCD supertile swizzle (round 6, +34%).
// Round 7: removed the lgkmcnt(0) pin before MFMA clusters (it serialized
// LDS-serve and MFMA: 1152+620=1772cyc/phase measured) and balanced reads
// to 8/4/8/4 per phase via bf0 pre-read in the ex-0-read phases.
#define BM 256
#define BN 256
#define BK 64
#define KT (DDIM / BK)            // 8 K-tiles
#define TILE_A_ELE (BM * BK)      // 16384 bf16 (A region; B same)
#define BUF_ELE (2 * TILE_A_ELE)  // A+B per buffer
#define LDS_BYTES (2 * BUF_ELE * 2)  // 131072

typedef __attribute__((ext_vector_type(8))) short short8;
typedef __attribute__((ext_vector_type(4))) float f32x4;

__device__ __forceinline__ void gload16(const __hip_bfloat16* g, __hip_bfloat16* l) {
  __builtin_amdgcn_global_load_lds(
      (const __attribute__((address_space(1))) void*)g,
      (__attribute__((address_space(3))) void*)l,
      16, 0, 0);
}

// -------------------------------------------------------------------------
// Kernel 1: row-normalize both inputs to bf16 (z1 additionally scaled by
// 1/temperature), zero the rowsum accumulator. One wave per row.
// -------------------------------------------------------------------------
__global__ __launch_bounds__(256) void normalize_rows(
    const float* __restrict__ z1, const float* __restrict__ z2,
    __hip_bfloat16* __restrict__ z1n, __hip_bfloat16* __restrict__ z2n,
    float* __restrict__ rowsum) {
  int row = blockIdx.x * 4 + (threadIdx.x >> 6);   // 0..16383
  int lane = threadIdx.x & 63;

  const float* src;
  __hip_bfloat16* dst;
  float numer;
  if (row < NROW) {
    src = z1 + (size_t)row * DDIM;
    dst = z1n + (size_t)row * DDIM;
    numer = TEMP_INV;
    if (lane == 0) rowsum[row] = 0.0f;
  } else {
    int r = row - NROW;
    src = z2 + (size_t)r * DDIM;
    dst = z2n + (size_t)r * DDIM;
    numer = 1.0f;
  }

  float4 v0 = *reinterpret_cast<const float4*>(src + lane * 8);
  float4 v1 = *reinterpret_cast<const float4*>(src + lane * 8 + 4);
  float ss = v0.x * v0.x + v0.y * v0.y + v0.z * v0.z + v0.w * v0.w +
             v1.x * v1.x + v1.y * v1.y + v1.z * v1.z + v1.w * v1.w;
#pragma unroll
  for (int off = 32; off; off >>= 1) ss += __shfl_xor(ss, off);

  float scale = numer / fmaxf(sqrtf(ss), 1e-8f);

  float vals[8] = {v0.x, v0.y, v0.z, v0.w, v1.x, v1.y, v1.z, v1.w};
  union { __hip_bfloat16 h[8]; uint4 q; } pk;
#pragma unroll
  for (int j = 0; j < 8; ++j) pk.h[j] = __float2bfloat16(vals[j] * scale);
  *reinterpret_cast<uint4*>(dst + lane * 8) = pk.q;
}

// -------------------------------------------------------------------------
// Kernel 2: fused GEMM (dots = z1n @ z2n^T) + exp epilogue + per-row
// sum-of-exp atomic accumulation. 8-phase pipelined 256x256 tile.
// LDS swizzle: LDS[row][slot'] holds global 16B-slot slot'^(row&7);
// staged via linear global_load_lds dest + pre-swizzled global source
// (0 conflicts, verified rounds 1/4/5/6).
// -------------------------------------------------------------------------
#define VMC(N) asm volatile("s_waitcnt vmcnt(" #N ")" ::: "memory")
#define SBAR()                          \
  do {                                  \
    __builtin_amdgcn_s_barrier();       \
    __builtin_amdgcn_sched_barrier(0);  \
  } while (0)

// 16B swizzled-slot LDS fragment loads (compile-time QM/QN/MI/NI/KK)
#define LDSA(BUFB, QM, MI, KK)                                                \
  (*reinterpret_cast<const short8*>(                                          \
      &lds[(size_t)(BUFB) * BUF_ELE +                                         \
           (wr * 128 + (QM) * 64 + (MI) * 16 + l15) * BK +                    \
           ((((KK) * 4 + hi) ^ x7) * 8)]))
#define LDSB(BUFB, QN, NI, KK)                                                \
  (*reinterpret_cast<const short8*>(                                          \
      &lds[(size_t)(BUFB) * BUF_ELE + TILE_A_ELE +                            \
           (wc * 64 + (QN) * 32 + (NI) * 16 + l15) * BK +                     \
           ((((KK) * 4 + hi) ^ x7) * 8)]))

// 4 MFMAs for one A row-block MI against a 4-frag B register set
#define MF4(QM, MI, QN, BF)                                                   \
  acc[(QM) * 4 + (MI)][(QN) * 2 + 0] =                                        \
      __builtin_amdgcn_mfma_f32_16x16x32_bf16(                                \
          af[(MI) * 2 + 0], (BF)[0], acc[(QM) * 4 + (MI)][(QN) * 2 + 0],      \
          0, 0, 0);                                                           \
  acc[(QM) * 4 + (MI)][(QN) * 2 + 0] =                                        \
      __builtin_amdgcn_mfma_f32_16x16x32_bf16(                                \
          af[(MI) * 2 + 1], (BF)[1], acc[(QM) * 4 + (MI)][(QN) * 2 + 0],      \
          0, 0, 0);                                                           \
  acc[(QM) * 4 + (MI)][(QN) * 2 + 1] =                                        \
      __builtin_amdgcn_mfma_f32_16x16x32_bf16(                                \
          af[(MI) * 2 + 0], (BF)[2], acc[(QM) * 4 + (MI)][(QN) * 2 + 1],      \
          0, 0, 0);                                                           \
  acc[(QM) * 4 + (MI)][(QN) * 2 + 1] =                                        \
      __builtin_amdgcn_mfma_f32_16x16x32_bf16(                                \
          af[(MI) * 2 + 1], (BF)[3], acc[(QM) * 4 + (MI)][(QN) * 2 + 1],      \
          0, 0, 0);

// A-phase: read 8 af frags (buf BUFB, quadrant QM), stage one half-tile,
// barrier, compute q(QM,0) against the live bf0. No manual lgkmcnt: the
// compiler emits per-operand counted waits, so early MFMAs overlap the
// LDS serve of later reads.
#define PHASE_A(BUFB, QM, ST, H)                                              \
  do {                                                                        \
    af[0] = LDSA(BUFB, QM, 0, 0); af[1] = LDSA(BUFB, QM, 0, 1);               \
    af[2] = LDSA(BUFB, QM, 1, 0); af[3] = LDSA(BUFB, QM, 1, 1);               \
    STAGE_HALF(ST, H);                                                        \
    af[4] = LDSA(BUFB, QM, 2, 0); af[5] = LDSA(BUFB, QM, 2, 1);               \
    af[6] = LDSA(BUFB, QM, 3, 0); af[7] = LDSA(BUFB, QM, 3, 1);               \
    SBAR();                                                                   \
    __builtin_amdgcn_s_setprio(1);                                            \
    MF4(QM, 0, 0, bf0) MF4(QM, 1, 0, bf0)                                     \
    MF4(QM, 2, 0, bf0) MF4(QM, 3, 0, bf0)                                     \
    __builtin_amdgcn_s_setprio(0);                                            \
    SBAR();                                                                   \
  } while (0)

// B-phase: read bf1 (qn=1), stage, barrier, compute q(0,1) w/ live af (=af0).
#define PHASE_B(BUFB, ST, H)                                                  \
  do {                                                                        \
    bf1[0] = LDSB(BUFB, 1, 0, 0); bf1[1] = LDSB(BUFB, 1, 0, 1);               \
    bf1[2] = LDSB(BUFB, 1, 1, 0); bf1[3] = LDSB(BUFB, 1, 1, 1);               \
    STAGE_HALF(ST, H);                                                        \
    SBAR();                                                                   \
    __builtin_amdgcn_s_setprio(1);                                            \
    MF4(0, 0, 1, bf1) MF4(0, 1, 1, bf1)                                       \
    MF4(0, 2, 1, bf1) MF4(0, 3, 1, bf1)                                       \
    __builtin_amdgcn_s_setprio(0);                                            \
    SBAR();                                                                   \
  } while (0)

// Wait-phase: stage next tile's h0, counted vmcnt proves current prefetch
// tile landed, barrier makes it visible, then PRE-READ its bf0 (qn=0) while
// computing q(1,1) w/ live af(=af1), bf1. bf0's old value died at ph3/ph7.
#define PHASE_W(ST, PBUF)                                                     \
  do {                                                                        \
    STAGE_HALF(ST, 0);                                                        \
    VMC(2);                                                                   \
    SBAR();                                                                   \
    bf0[0] = LDSB(PBUF, 0, 0, 0); bf0[1] = LDSB(PBUF, 0, 0, 1);               \
    bf0[2] = LDSB(PBUF, 0, 1, 0); bf0[3] = LDSB(PBUF, 0, 1, 1);               \
    __builtin_amdgcn_s_setprio(1);                                            \
    MF4(1, 0, 1, bf1) MF4(1, 1, 1, bf1)                                       \
    MF4(1, 2, 1, bf1) MF4(1, 3, 1, bf1)                                       \
    __builtin_amdgcn_s_setprio(0);                                            \
    SBAR();                                                                   \
  } while (0)

__global__ __launch_bounds__(512, 2) void gemm_lse(
    const __hip_bfloat16* __restrict__ An,   // z1n [N][D]
    const __hip_bfloat16* __restrict__ Bn,   // z2n [N][D]
    float* __restrict__ rowsum) {
  extern __shared__ __align__(16) __hip_bfloat16 lds[];

  // ---- XCD-aware supertile swizzle (bijective over the 32x32 grid) ----
  const int bid = blockIdx.x;
  const int chunk = bid & 7;          // XCD id (round-robin dispatch)
  const int slot = bid >> 3;          // 0..127: per-XCD issue order
  const int by = chunk * 4 + ((slot >> 2) & 3);
  const int bx = (slot >> 4) * 4 + (slot & 3);
  const int brow = by * BM;
  const int bcol = bx * BN;

  const int tid = threadIdx.x;
  const int w = tid >> 6;             // wave 0..7
  const int lane = tid & 63;
  const int wr = w >> 2;              // 0..1: rows [wr*128, +128)
  const int wc = w & 3;               // 0..3: cols [wc*64, +64)

  f32x4 acc[8][4];
#pragma unroll
  for (int m = 0; m < 8; ++m)
#pragma unroll
    for (int n = 0; n < 4; ++n) acc[m][n] = (f32x4)0.0f;

  // ---- staging (per-wave: 2 gloads per half; halves: 0=Atop 1=Abot 2=Btop 3=Bbot)
  const int srow8 = lane >> 3;               // 0..7
  const int sslot = (lane & 7) ^ srow8;      // pre-swizzled source slot

  auto STAGE_HALF = [&](int st, int h) {
    const int stm = st & (KT - 1);           // wrap: dead prefetch on last iter
    const __hip_bfloat16* gbase =
        (h < 2) ? An + (size_t)brow * DDIM : Bn + (size_t)bcol * DDIM;
    const int rowt = (h & 1) * 128 + w * 16; // row within 256-row tile
    const __hip_bfloat16* g =
        gbase + (size_t)(rowt + srow8) * DDIM + stm * BK + sslot * 8;
    __hip_bfloat16* dst = lds + (size_t)(stm & 1) * BUF_ELE +
                          ((h >= 2) ? TILE_A_ELE : 0) + rowt * BK;
    gload16(g, dst);
    gload16(g + (size_t)8 * DDIM, dst + 8 * BK);
  };

  const int hi = lane >> 4;    // 0..3
  const int l15 = lane & 15;
  const int x7 = lane & 7;

  // ---- prologue: tile0 fully + tile1 h0; wait tile0, pre-read its bf0 ----
  STAGE_HALF(0, 0); STAGE_HALF(0, 1); STAGE_HALF(0, 2); STAGE_HALF(0, 3);
  STAGE_HALF(1, 0);
  VMC(2);                              // tile0's 4 halves (8 loads) landed
  SBAR();

  short8 af[8], bf0[4], bf1[4];
  bf0[0] = LDSB(0, 0, 0, 0); bf0[1] = LDSB(0, 0, 0, 1);
  bf0[2] = LDSB(0, 0, 1, 0); bf0[3] = LDSB(0, 0, 1, 1);

  for (int i = 0; i < KT / 2; ++i) {
    // Tiles: T0 = 2i (buf0, ph1-4), T1 = 2i+1 (buf1, ph5-8).
    const int t1 = 2 * i + 1, t2 = 2 * i + 2, t3 = 2 * i + 3;
    PHASE_A(0, 0, t1, 1);   // ph1: read af0(buf0), q(0,0) w/ pre-read bf0
    PHASE_B(0, t1, 2);      // ph2: read bf1(buf0), q(0,1)
    PHASE_A(0, 1, t1, 3);   // ph3: read af1(buf0), q(1,0) w/ bf0
    PHASE_W(t2, 1);         // ph4: q(1,1) w/ bf1; pre-read bf0 <- buf1(T1)
    PHASE_A(1, 0, t2, 1);   // ph5: read af0(buf1), q(0,0)
    PHASE_B(1, t2, 2);      // ph6: read bf1(buf1), q(0,1)
    PHASE_A(1, 1, t2, 3);   // ph7: read af1(buf1), q(1,0)
    PHASE_W(t3, 0);         // ph8: q(1,1); pre-read bf0 <- buf0(T2)
  }

  // ---- epilogue: exp(sim - 20), 16-lane col reduce, atomic accumulate ----
  // C/D layout: col = lane&15, row = (lane>>4)*4 + reg  [m89/m91]
  const float L2E = 1.4426950408889634f;
  const float NEG = -SHIFT * 1.4426950408889634f;
#pragma unroll
  for (int m = 0; m < 8; ++m) {
#pragma unroll
    for (int r = 0; r < 4; ++r) {
      float s = 0.0f;
#pragma unroll
      for (int n = 0; n < 4; ++n)
        s += exp2f(fmaf(acc[m][n][r], L2E, NEG));
      s += __shfl_xor(s, 1);
      s += __shfl_xor(s, 2);
      s += __shfl_xor(s, 4);
      s += __shfl_xor(s, 8);
      if (l15 == 0)
        atomicAdd(&rowsum[brow + wr * 128 + m * 16 + hi * 4 + r], s);
    }
  }
}

// -------------------------------------------------------------------------
// Kernel 3: out = -( mean_i( log(rowsum_i) + 20 ) )
// -------------------------------------------------------------------------
__global__ __launch_bounds__(1024) void finalize_lse(
    const float* __restrict__ rowsum, float* __restrict__ out) {
  __shared__ float sm[16];
  float s = 0.0f;
  for (int i = threadIdx.x; i < NROW; i += 1024) s += logf(rowsum[i]);
#pragma unroll
  for (int off = 32; off; off >>= 1) s += __shfl_xor(s, off);
  int w = threadIdx.x >> 6;
  if ((threadIdx.x & 63) == 0) sm[w] = s;
  __syncthreads();
  if (threadIdx.x == 0) {
    float t = 0.0f;
#pragma unroll
    for (int i = 0; i < 16; ++i) t += sm[i];
    out[0] = -(t / (float)NROW + SHIFT);
  }
}

// -------------------------------------------------------------------------
extern "C" void kernel_launch(void* const* d_in, const int* in_sizes, int n_in,
                              void* d_out, int out_size, void* d_ws,
                              size_t ws_size, hipStream_t stream) {
  const float* z1 = (const float*)d_in[0];
  const float* z2 = (const float*)d_in[1];
  float* out = (float*)d_out;

  char* ws = (char*)d_ws;
  __hip_bfloat16* z1n = (__hip_bfloat16*)ws;                               // 8 MB
  __hip_bfloat16* z2n = (__hip_bfloat16*)(ws + (size_t)NROW * DDIM * 2);   // 8 MB
  float* rowsum = (float*)(ws + (size_t)2 * NROW * DDIM * 2);              // 32 KB

  static bool attr_set = false;
  if (!attr_set) {
    hipFuncSetAttribute((const void*)gemm_lse,
                        hipFuncAttributeMaxDynamicSharedMemorySize, LDS_BYTES);
    attr_set = true;
  }

  normalize_rows<<<dim3((2 * NROW) / 4), dim3(256), 0, stream>>>(z1, z2, z1n,
                                                                 z2n, rowsum);
  gemm_lse<<<dim3((NROW / BM) * (NROW / BN)), dim3(512), LDS_BYTES, stream>>>(
      z1n, z2n, rowsum);
  finalize_lse<<<dim3(1), dim3(1024), 0, stream>>>(rowsum, out);
}